// Round 1
// baseline (270.007 us; speedup 1.0000x reference)
//
#include <hip/hip_runtime.h>

typedef unsigned int uint32;

#define NN 2048
#define FF 128
#define KEEPK 1258291u      // int(0.3 * 2048 * 2048)
#define NB 2048             // histogram bins per level
#define LO1 (-4.0f)
#define BINW1 0.0625f       // 2^-4, exact
#define INV1 16.0f
#define INV2 32768.0f       // 1 / (BINW1/2048) = 2^15, exact
#define CAND_CAP 16384

// workspace layout (bytes)
#define OFF_DEG   (0u)              // float[2048]
#define OFF_DINV  (8u*1024u)        // float[2048]
#define OFF_HIST1 (16u*1024u)       // uint[2048]
#define OFF_HIST2 (24u*1024u)       // uint[2048]
#define OFF_SCAL  (32u*1024u)       // uint[64]: 0=B1 1=K2 2=B2 3=need 5=cand_count 6=tau_bits 7=cutoff
#define OFF_CANDV (40u*1024u)       // float[CAND_CAP]
#define OFF_CANDF (104u*1024u)      // uint[CAND_CAP]
#define OFF_ACC   (168u*1024u)      // float[2048*128] = 1 MB
#define OFF_H     (1192u*1024u)     // float[2048*128] = 1 MB
#define OFF_S     (2216u*1024u)     // float[2048*2048] = 16 MB
#define WS_NEEDED ((size_t)OFF_S + (size_t)NN*NN*4u)
#define ZERO_BYTES OFF_H            // zero deg/hists/scal/cand/acc each call

__device__ __forceinline__ int bin_of(float v, float lo, float inv) {
    int b = (int)floorf((v - lo) * inv);
    return b < 0 ? 0 : (b > NB - 1 ? NB - 1 : b);
}

// h = X * W   [2048x128] = [2048x128][128x128]
__global__ __launch_bounds__(128) void k_h(const float* __restrict__ x,
                                           const float* __restrict__ W,
                                           float* __restrict__ h) {
    __shared__ float xs[FF];
    int row = blockIdx.x;
    int f = threadIdx.x;
    xs[f] = x[row * FF + f];
    __syncthreads();
    float a0 = 0.f, a1 = 0.f, a2 = 0.f, a3 = 0.f;
    #pragma unroll 8
    for (int k = 0; k < FF; k += 4) {
        a0 += xs[k + 0] * W[(k + 0) * FF + f];
        a1 += xs[k + 1] * W[(k + 1) * FF + f];
        a2 += xs[k + 2] * W[(k + 2) * FF + f];
        a3 += xs[k + 3] * W[(k + 3) * FF + f];
    }
    h[row * FF + f] = (a0 + a1) + (a2 + a3);
}

// S = X * X^T - I.  64x64 tile per block, XOR-swizzled LDS, b128 reads.
__global__ __launch_bounds__(256) void k_sim(const float* __restrict__ x,
                                             float* __restrict__ S) {
    __shared__ float As[64 * 128];   // 32 KB, [row][k] with chunk-XOR swizzle
    __shared__ float Bs[64 * 128];   // 32 KB
    int t = threadIdx.x;
    int i0 = blockIdx.y * 64, j0 = blockIdx.x * 64;
    int rr = t >> 5, cc = t & 31;
    #pragma unroll
    for (int u = 0; u < 8; ++u) {
        int row = rr + u * 8;
        int cp = (cc ^ ((row >> 2) & 7)) * 4;
        float4 a = *(const float4*)&x[(size_t)(i0 + row) * FF + cc * 4];
        *(float4*)&As[row * 128 + cp] = a;
        float4 b = *(const float4*)&x[(size_t)(j0 + row) * FF + cc * 4];
        *(float4*)&Bs[row * 128 + cp] = b;
    }
    __syncthreads();

    int ig = t & 15, jg = t >> 4;
    int swA = ig & 7, swB = jg & 7;
    float acc[4][4];
    #pragma unroll
    for (int r = 0; r < 4; ++r)
        #pragma unroll
        for (int c = 0; c < 4; ++c) acc[r][c] = 0.f;

    #pragma unroll 2
    for (int kc = 0; kc < 32; ++kc) {
        float4 av[4], bv[4];
        int ca = (kc ^ swA) * 4;
        int cb = (kc ^ swB) * 4;
        #pragma unroll
        for (int r = 0; r < 4; ++r) av[r] = *(float4*)&As[(ig * 4 + r) * 128 + ca];
        #pragma unroll
        for (int r = 0; r < 4; ++r) bv[r] = *(float4*)&Bs[(jg * 4 + r) * 128 + cb];
        #pragma unroll
        for (int r = 0; r < 4; ++r)
            #pragma unroll
            for (int c = 0; c < 4; ++c)
                acc[r][c] += av[r].x * bv[c].x + av[r].y * bv[c].y +
                             av[r].z * bv[c].z + av[r].w * bv[c].w;
    }

    #pragma unroll
    for (int r = 0; r < 4; ++r) {
        int gi = i0 + ig * 4 + r;
        float4 o;
        o.x = acc[r][0]; o.y = acc[r][1]; o.z = acc[r][2]; o.w = acc[r][3];
        int d = gi - (j0 + jg * 4);
        if (d >= 0 && d < 4) (&o.x)[d] -= 1.0f;   // subtract eye
        *(float4*)&S[(size_t)gi * NN + j0 + jg * 4] = o;
    }
}

// histogram (level 1: coarse bins over [-4,124); level 2: refine bin B1)
__global__ __launch_bounds__(256) void k_hist(const float4* __restrict__ S4,
                                              uint32* __restrict__ hist,
                                              const uint32* __restrict__ scal,
                                              int level) {
    __shared__ uint32 hs[NB];
    int t = threadIdx.x;
    for (int i = t; i < NB; i += blockDim.x) hs[i] = 0;
    __syncthreads();
    int B1 = 0; float lo2 = 0.f;
    if (level == 2) { B1 = (int)scal[0]; lo2 = LO1 + (float)B1 * BINW1; }
    int total4 = (NN * NN) / 4;
    for (int idx = blockIdx.x * blockDim.x + t; idx < total4; idx += gridDim.x * blockDim.x) {
        float4 v = S4[idx];
        #pragma unroll
        for (int c = 0; c < 4; ++c) {
            float xv = (&v.x)[c];
            int b1 = bin_of(xv, LO1, INV1);
            if (level == 1) {
                atomicAdd(&hs[b1], 1u);
            } else if (b1 == B1) {
                int b2 = bin_of(xv, lo2, INV2);
                atomicAdd(&hs[b2], 1u);
            }
        }
    }
    __syncthreads();
    for (int i = t; i < NB; i += blockDim.x) {
        uint32 v = hs[i];
        if (v) atomicAdd(&hist[i], v);
    }
}

// find bin containing K-th largest (descending cumulative)
__global__ __launch_bounds__(256) void k_scan(const uint32* __restrict__ hist,
                                              uint32* __restrict__ scal, int level) {
    __shared__ uint32 csum[256];
    int t = threadIdx.x;
    uint32 s = 0;
    #pragma unroll
    for (int u = 0; u < 8; ++u) s += hist[t * 8 + u];
    csum[t] = s;
    __syncthreads();
    if (t == 0) {
        uint32 K = (level == 1) ? KEEPK : scal[1];
        uint32 cum = 0;
        int cb = 255;
        for (; cb > 0; --cb) {
            if (cum + csum[cb] >= K) break;
            cum += csum[cb];
        }
        int b;
        for (b = cb * 8 + 7; b > cb * 8; --b) {
            if (cum + hist[b] >= K) break;
            cum += hist[b];
        }
        if (level == 1) { scal[0] = (uint32)b; scal[1] = K - cum; }
        else           { scal[2] = (uint32)b; scal[3] = K - cum; }
    }
}

// gather candidate (value, flat index) pairs in the final bin
__global__ __launch_bounds__(256) void k_cand(const float* __restrict__ S,
                                              float* __restrict__ candV,
                                              uint32* __restrict__ candF,
                                              uint32* __restrict__ scal) {
    int B1 = (int)scal[0], B2 = (int)scal[2];
    float lo2 = LO1 + (float)B1 * BINW1;
    int total = NN * NN;
    for (int idx = blockIdx.x * blockDim.x + threadIdx.x; idx < total;
         idx += gridDim.x * blockDim.x) {
        float v = S[idx];
        int b1 = bin_of(v, LO1, INV1);
        if (b1 == B1) {
            int b2 = bin_of(v, lo2, INV2);
            if (b2 == B2) {
                uint32 p = atomicAdd(&scal[5], 1u);
                if (p < CAND_CAP) { candV[p] = v; candF[p] = (uint32)idx; }
            }
        }
    }
}

// exact tau + tie cutoff: partial selection sort (desc value, asc flat idx)
__global__ __launch_bounds__(256) void k_pick(const float* __restrict__ candV,
                                              const uint32* __restrict__ candF,
                                              uint32* __restrict__ scal) {
    __shared__ float sv[4096];
    __shared__ uint32 sf[4096];
    int t = threadIdx.x;
    uint32 cnt = scal[5];
    if (cnt > 4096u) cnt = 4096u;
    for (uint32 i = t; i < cnt; i += 256u) { sv[i] = candV[i]; sf[i] = candF[i]; }
    __syncthreads();
    if (t == 0) {
        uint32 need = scal[3];
        if (need > cnt) need = cnt;
        if (cnt == 0) { scal[6] = __float_as_uint(3.0e38f); scal[7] = 0u; return; }
        if (need == 0) need = 1;
        for (uint32 s = 0; s < need; ++s) {
            uint32 best = s;
            for (uint32 q = s + 1; q < cnt; ++q) {
                if (sv[q] > sv[best] || (sv[q] == sv[best] && sf[q] < sf[best])) best = q;
            }
            float tv = sv[s]; sv[s] = sv[best]; sv[best] = tv;
            uint32 tf = sf[s]; sf[s] = sf[best]; sf[best] = tf;
        }
        scal[6] = __float_as_uint(sv[need - 1]);
        scal[7] = sf[need - 1];
    }
}

// deg[j] = sum of selected sim[i][j] over i (self-loop +1 added in k_dinv)
__global__ __launch_bounds__(256) void k_deg(const float* __restrict__ S,
                                             const uint32* __restrict__ scal,
                                             float* __restrict__ deg) {
    int j = blockIdx.x * 256 + threadIdx.x;
    int i0 = blockIdx.y * 64;
    float tau = __uint_as_float(scal[6]);
    uint32 cutoff = scal[7];
    float p = 0.f;
    #pragma unroll 4
    for (int ii = 0; ii < 64; ++ii) {
        int i = i0 + ii;
        float v = S[(size_t)i * NN + j];
        uint32 flat = (uint32)(i * NN + j);
        if (v > tau || (v == tau && flat <= cutoff)) p += v;
    }
    atomicAdd(&deg[j], p);
}

__global__ __launch_bounds__(256) void k_dinv(const float* __restrict__ deg,
                                              float* __restrict__ dinv) {
    int j = blockIdx.x * 256 + threadIdx.x;
    dinv[j] = rsqrtf(deg[j] + 1.0f);   // +1.0 = self-loop; always > 0
}

// acc[j][f] += sum_i sel(i,j) * S[i][j] * dinv[i] * h[i][f]
__global__ __launch_bounds__(256) void k_agg(const float* __restrict__ S,
                                             const float* __restrict__ h,
                                             const float* __restrict__ dinv,
                                             const uint32* __restrict__ scal,
                                             float* __restrict__ accb) {
    __shared__ float wsm[32][68];    // [ii][jj], padded
    __shared__ float hsm[32][132];   // [ii][f], padded
    int t = threadIdx.x;
    int j0 = blockIdx.x * 64;
    int ibase = blockIdx.y * 128;
    float tau = __uint_as_float(scal[6]);
    uint32 cutoff = scal[7];
    int jg = t & 15, fg = t >> 4;

    float acc[4][8];
    #pragma unroll
    for (int a = 0; a < 4; ++a)
        #pragma unroll
        for (int bq = 0; bq < 8; ++bq) acc[a][bq] = 0.f;

    for (int ccnk = 0; ccnk < 4; ++ccnk) {
        int ib = ibase + ccnk * 32;
        #pragma unroll
        for (int r = 0; r < 8; ++r) {
            int idx = r * 256 + t;
            int ii = idx >> 6, jj = idx & 63;
            int gi = ib + ii, gj = j0 + jj;
            float v = S[(size_t)gi * NN + gj];
            uint32 flat = (uint32)(gi * NN + gj);
            bool sel = (v > tau) || (v == tau && flat <= cutoff);
            wsm[ii][jj] = sel ? v * dinv[gi] : 0.f;
        }
        #pragma unroll
        for (int r = 0; r < 4; ++r) {
            int fidx = r * 256 + t;
            int ii = fidx >> 5, f4 = fidx & 31;
            *(float4*)&hsm[ii][f4 * 4] = *(const float4*)&h[(size_t)(ib + ii) * FF + f4 * 4];
        }
        __syncthreads();
        #pragma unroll 4
        for (int ii = 0; ii < 32; ++ii) {
            float4 w = *(float4*)&wsm[ii][jg * 4];
            float4 h0 = *(float4*)&hsm[ii][fg * 8];
            float4 h1 = *(float4*)&hsm[ii][fg * 8 + 4];
            float wv[4] = {w.x, w.y, w.z, w.w};
            float hv[8] = {h0.x, h0.y, h0.z, h0.w, h1.x, h1.y, h1.z, h1.w};
            #pragma unroll
            for (int a = 0; a < 4; ++a)
                #pragma unroll
                for (int bq = 0; bq < 8; ++bq) acc[a][bq] += wv[a] * hv[bq];
        }
        __syncthreads();
    }
    #pragma unroll
    for (int a = 0; a < 4; ++a) {
        int gj = j0 + jg * 4 + a;
        #pragma unroll
        for (int bq = 0; bq < 8; ++bq)
            atomicAdd(&accb[(size_t)gj * FF + fg * 8 + bq], acc[a][bq]);
    }
}

// out[j][f] = b[f] + dinv[j] * (dinv[j]*h[j][f] + acc[j][f])
__global__ __launch_bounds__(256) void k_final(const float* __restrict__ accb,
                                               const float* __restrict__ h,
                                               const float* __restrict__ dinv,
                                               const float* __restrict__ bvec,
                                               float* __restrict__ out) {
    int idx4 = blockIdx.x * 256 + threadIdx.x;   // 65536 float4s
    int j = idx4 >> 5;
    int f4 = (idx4 & 31) * 4;
    float dj = dinv[j];
    float4 a = *(const float4*)&accb[(size_t)j * FF + f4];
    float4 hv = *(const float4*)&h[(size_t)j * FF + f4];
    float4 bv = *(const float4*)&bvec[f4];
    float4 o;
    o.x = bv.x + dj * (dj * hv.x + a.x);
    o.y = bv.y + dj * (dj * hv.y + a.y);
    o.z = bv.z + dj * (dj * hv.z + a.z);
    o.w = bv.w + dj * (dj * hv.w + a.w);
    *(float4*)&out[(size_t)j * FF + f4] = o;
}

extern "C" void kernel_launch(void* const* d_in, const int* in_sizes, int n_in,
                              void* d_out, int out_size, void* d_ws, size_t ws_size,
                              hipStream_t stream) {
    const float* x = (const float*)d_in[0];   // [1,2048,128]
    const float* W = (const float*)d_in[1];   // [128,128]
    const float* b = (const float*)d_in[2];   // [128]
    float* out = (float*)d_out;

    if (ws_size < WS_NEEDED) return;  // insufficient scratch: fail visibly

    char* ws = (char*)d_ws;
    float*  deg   = (float*)(ws + OFF_DEG);
    float*  dinv  = (float*)(ws + OFF_DINV);
    uint32* hist1 = (uint32*)(ws + OFF_HIST1);
    uint32* hist2 = (uint32*)(ws + OFF_HIST2);
    uint32* scal  = (uint32*)(ws + OFF_SCAL);
    float*  candV = (float*)(ws + OFF_CANDV);
    uint32* candF = (uint32*)(ws + OFF_CANDF);
    float*  accb  = (float*)(ws + OFF_ACC);
    float*  h     = (float*)(ws + OFF_H);
    float*  S     = (float*)(ws + OFF_S);

    hipMemsetAsync(ws, 0, ZERO_BYTES, stream);

    k_h<<<NN, 128, 0, stream>>>(x, W, h);
    k_sim<<<dim3(32, 32), 256, 0, stream>>>(x, S);
    k_hist<<<512, 256, 0, stream>>>((const float4*)S, hist1, scal, 1);
    k_scan<<<1, 256, 0, stream>>>(hist1, scal, 1);
    k_hist<<<512, 256, 0, stream>>>((const float4*)S, hist2, scal, 2);
    k_scan<<<1, 256, 0, stream>>>(hist2, scal, 2);
    k_cand<<<512, 256, 0, stream>>>(S, candV, candF, scal);
    k_pick<<<1, 256, 0, stream>>>(candV, candF, scal);
    k_deg<<<dim3(8, 32), 256, 0, stream>>>(S, scal, deg);
    k_dinv<<<8, 256, 0, stream>>>(deg, dinv);
    k_agg<<<dim3(32, 16), 256, 0, stream>>>(S, h, dinv, scal, accb);
    k_final<<<256, 256, 0, stream>>>(accb, h, dinv, b, out);
}

// Round 2
// 147.705 us; speedup vs baseline: 1.8280x; 1.8280x over previous
//
#include <hip/hip_runtime.h>

typedef unsigned int uint32;

#define NN 2048
#define FF 128
#define KEEPK 1258291u      // int(0.3 * 2048 * 2048)
#define NB 2048             // histogram bins per level
#define LO1 (-4.0f)
#define BINW1 0.0625f       // 2^-4, exact
#define INV1 16.0f
#define INV2 32768.0f       // 1 / (BINW1/2048) = 2^15, exact
#define CAND_CAP 16384
#define NPART 8             // i-chunks for atomic-free aggregation

// workspace layout (bytes)
#define OFF_DEG   (0u)              // float[2048]
#define OFF_DINV  (8u*1024u)        // float[2048]
#define OFF_HIST1 (16u*1024u)       // uint[2048]
#define OFF_HIST2 (24u*1024u)       // uint[2048]
#define OFF_SCAL  (32u*1024u)       // uint[64]
#define OFF_CANDV (40u*1024u)       // float[CAND_CAP]
#define OFF_CANDF (104u*1024u)      // uint[CAND_CAP]
#define OFF_ACC   (168u*1024u)      // float[2048*128] = 1 MB (atomic fallback only)
#define OFF_H     (1192u*1024u)     // float[2048*128] = 1 MB
#define OFF_S     (2216u*1024u)     // float[2048*2048] = 16 MB
#define OFF_PART  (OFF_S + (uint32)NN*NN*4u)          // float[NPART][2048][128] = 8 MB
#define WS_NEEDED_ATOMIC ((size_t)OFF_S + (size_t)NN*NN*4u)
#define WS_NEEDED_PART   ((size_t)OFF_PART + (size_t)NPART*NN*FF*4u)
#define ZERO_BYTES OFF_H            // zero deg/hists/scal/cand/acc each call

__device__ __forceinline__ int bin_of(float v, float lo, float inv) {
    int b = (int)floorf((v - lo) * inv);
    return b < 0 ? 0 : (b > NB - 1 ? NB - 1 : b);
}

// h = X * W   [2048x128] = [2048x128][128x128]
__global__ __launch_bounds__(128) void k_h(const float* __restrict__ x,
                                           const float* __restrict__ W,
                                           float* __restrict__ h) {
    __shared__ float xs[FF];
    int row = blockIdx.x;
    int f = threadIdx.x;
    xs[f] = x[row * FF + f];
    __syncthreads();
    float a0 = 0.f, a1 = 0.f, a2 = 0.f, a3 = 0.f;
    #pragma unroll 8
    for (int k = 0; k < FF; k += 4) {
        a0 += xs[k + 0] * W[(k + 0) * FF + f];
        a1 += xs[k + 1] * W[(k + 1) * FF + f];
        a2 += xs[k + 2] * W[(k + 2) * FF + f];
        a3 += xs[k + 3] * W[(k + 3) * FF + f];
    }
    h[row * FF + f] = (a0 + a1) + (a2 + a3);
}

// S = X * X^T - I, fused with the level-1 histogram (saves a 16MB S pass).
__global__ __launch_bounds__(256) void k_sim(const float* __restrict__ x,
                                             float* __restrict__ S,
                                             uint32* __restrict__ hist1) {
    __shared__ float As[64 * 128];   // 32 KB, [row][k] with chunk-XOR swizzle
    __shared__ float Bs[64 * 128];   // 32 KB
    __shared__ uint32 hs[NB];        // 8 KB
    int t = threadIdx.x;
    for (int i = t; i < NB; i += 256) hs[i] = 0;
    int i0 = blockIdx.y * 64, j0 = blockIdx.x * 64;
    int rr = t >> 5, cc = t & 31;
    #pragma unroll
    for (int u = 0; u < 8; ++u) {
        int row = rr + u * 8;
        int cp = (cc ^ ((row >> 2) & 7)) * 4;
        float4 a = *(const float4*)&x[(size_t)(i0 + row) * FF + cc * 4];
        *(float4*)&As[row * 128 + cp] = a;
        float4 b = *(const float4*)&x[(size_t)(j0 + row) * FF + cc * 4];
        *(float4*)&Bs[row * 128 + cp] = b;
    }
    __syncthreads();

    int ig = t & 15, jg = t >> 4;
    int swA = ig & 7, swB = jg & 7;
    float acc[4][4];
    #pragma unroll
    for (int r = 0; r < 4; ++r)
        #pragma unroll
        for (int c = 0; c < 4; ++c) acc[r][c] = 0.f;

    #pragma unroll 2
    for (int kc = 0; kc < 32; ++kc) {
        float4 av[4], bv[4];
        int ca = (kc ^ swA) * 4;
        int cb = (kc ^ swB) * 4;
        #pragma unroll
        for (int r = 0; r < 4; ++r) av[r] = *(float4*)&As[(ig * 4 + r) * 128 + ca];
        #pragma unroll
        for (int r = 0; r < 4; ++r) bv[r] = *(float4*)&Bs[(jg * 4 + r) * 128 + cb];
        #pragma unroll
        for (int r = 0; r < 4; ++r)
            #pragma unroll
            for (int c = 0; c < 4; ++c)
                acc[r][c] += av[r].x * bv[c].x + av[r].y * bv[c].y +
                             av[r].z * bv[c].z + av[r].w * bv[c].w;
    }

    #pragma unroll
    for (int r = 0; r < 4; ++r) {
        int gi = i0 + ig * 4 + r;
        float4 o;
        o.x = acc[r][0]; o.y = acc[r][1]; o.z = acc[r][2]; o.w = acc[r][3];
        int d = gi - (j0 + jg * 4);
        if (d >= 0 && d < 4) (&o.x)[d] -= 1.0f;   // subtract eye
        *(float4*)&S[(size_t)gi * NN + j0 + jg * 4] = o;
        #pragma unroll
        for (int c = 0; c < 4; ++c)
            atomicAdd(&hs[bin_of((&o.x)[c], LO1, INV1)], 1u);
    }
    __syncthreads();
    for (int i = t; i < NB; i += 256) {
        uint32 v = hs[i];
        if (v) atomicAdd(&hist1[i], v);
    }
}

// level-2 histogram: refine bin B1
__global__ __launch_bounds__(256) void k_hist2(const float4* __restrict__ S4,
                                               uint32* __restrict__ hist,
                                               const uint32* __restrict__ scal) {
    __shared__ uint32 hs[NB];
    int t = threadIdx.x;
    for (int i = t; i < NB; i += blockDim.x) hs[i] = 0;
    __syncthreads();
    int B1 = (int)scal[0];
    float lo2 = LO1 + (float)B1 * BINW1;
    int total4 = (NN * NN) / 4;
    for (int idx = blockIdx.x * blockDim.x + t; idx < total4; idx += gridDim.x * blockDim.x) {
        float4 v = S4[idx];
        #pragma unroll
        for (int c = 0; c < 4; ++c) {
            float xv = (&v.x)[c];
            if (bin_of(xv, LO1, INV1) == B1) {
                atomicAdd(&hs[bin_of(xv, lo2, INV2)], 1u);
            }
        }
    }
    __syncthreads();
    for (int i = t; i < NB; i += blockDim.x) {
        uint32 v = hs[i];
        if (v) atomicAdd(&hist[i], v);
    }
}

// find bin containing K-th largest (descending cumulative)
__global__ __launch_bounds__(256) void k_scan(const uint32* __restrict__ hist,
                                              uint32* __restrict__ scal, int level) {
    __shared__ uint32 csum[256];
    int t = threadIdx.x;
    uint32 s = 0;
    #pragma unroll
    for (int u = 0; u < 8; ++u) s += hist[t * 8 + u];
    csum[t] = s;
    __syncthreads();
    if (t == 0) {
        uint32 K = (level == 1) ? KEEPK : scal[1];
        uint32 cum = 0;
        int cb = 255;
        for (; cb > 0; --cb) {
            if (cum + csum[cb] >= K) break;
            cum += csum[cb];
        }
        int b;
        for (b = cb * 8 + 7; b > cb * 8; --b) {
            if (cum + hist[b] >= K) break;
            cum += hist[b];
        }
        if (level == 1) { scal[0] = (uint32)b; scal[1] = K - cum; }
        else           { scal[2] = (uint32)b; scal[3] = K - cum; }
    }
}

// gather candidate (value, flat index) pairs in the final bin
__global__ __launch_bounds__(256) void k_cand(const float* __restrict__ S,
                                              float* __restrict__ candV,
                                              uint32* __restrict__ candF,
                                              uint32* __restrict__ scal) {
    int B1 = (int)scal[0], B2 = (int)scal[2];
    float lo2 = LO1 + (float)B1 * BINW1;
    int total = NN * NN;
    for (int idx = blockIdx.x * blockDim.x + threadIdx.x; idx < total;
         idx += gridDim.x * blockDim.x) {
        float v = S[idx];
        if (bin_of(v, LO1, INV1) == B1 && bin_of(v, lo2, INV2) == B2) {
            uint32 p = atomicAdd(&scal[5], 1u);
            if (p < CAND_CAP) { candV[p] = v; candF[p] = (uint32)idx; }
        }
    }
}

// exact tau + tie cutoff: partial selection sort (desc value, asc flat idx)
__global__ __launch_bounds__(256) void k_pick(const float* __restrict__ candV,
                                              const uint32* __restrict__ candF,
                                              uint32* __restrict__ scal) {
    __shared__ float sv[4096];
    __shared__ uint32 sf[4096];
    int t = threadIdx.x;
    uint32 cnt = scal[5];
    if (cnt > 4096u) cnt = 4096u;
    for (uint32 i = t; i < cnt; i += 256u) { sv[i] = candV[i]; sf[i] = candF[i]; }
    __syncthreads();
    if (t == 0) {
        uint32 need = scal[3];
        if (need > cnt) need = cnt;
        if (cnt == 0) { scal[6] = __float_as_uint(3.0e38f); scal[7] = 0u; return; }
        if (need == 0) need = 1;
        for (uint32 s = 0; s < need; ++s) {
            uint32 best = s;
            for (uint32 q = s + 1; q < cnt; ++q) {
                if (sv[q] > sv[best] || (sv[q] == sv[best] && sf[q] < sf[best])) best = q;
            }
            float tv = sv[s]; sv[s] = sv[best]; sv[best] = tv;
            uint32 tf = sf[s]; sf[s] = sf[best]; sf[best] = tf;
        }
        scal[6] = __float_as_uint(sv[need - 1]);
        scal[7] = sf[need - 1];
    }
}

// deg[j] = sum of selected sim[i][j] over i (self-loop +1 added in k_dinv)
__global__ __launch_bounds__(256) void k_deg(const float* __restrict__ S,
                                             const uint32* __restrict__ scal,
                                             float* __restrict__ deg) {
    int j = blockIdx.x * 256 + threadIdx.x;
    int i0 = blockIdx.y * 64;
    float tau = __uint_as_float(scal[6]);
    uint32 cutoff = scal[7];
    float p = 0.f;
    #pragma unroll 4
    for (int ii = 0; ii < 64; ++ii) {
        int i = i0 + ii;
        float v = S[(size_t)i * NN + j];
        uint32 flat = (uint32)(i * NN + j);
        if (v > tau || (v == tau && flat <= cutoff)) p += v;
    }
    atomicAdd(&deg[j], p);
}

__global__ __launch_bounds__(256) void k_dinv(const float* __restrict__ deg,
                                              float* __restrict__ dinv) {
    int j = blockIdx.x * 256 + threadIdx.x;
    dinv[j] = rsqrtf(deg[j] + 1.0f);   // +1.0 = self-loop; always > 0
}

// part[by][j][f] = sum_{i in chunk by} sel(i,j) * S[i][j] * dinv[i] * h[i][f]
// Atomic-free: each block owns a distinct (j-tile, i-chunk) partial slice.
__global__ __launch_bounds__(256) void k_agg_part(const float* __restrict__ S,
                                                  const float* __restrict__ h,
                                                  const float* __restrict__ dinv,
                                                  const uint32* __restrict__ scal,
                                                  float* __restrict__ part) {
    __shared__ float wsm[32][68];    // [ii][jj], padded
    __shared__ float hsm[32][132];   // [ii][f], padded
    int t = threadIdx.x;
    int j0 = blockIdx.x * 64;
    int by = blockIdx.y;
    int ibase = by * (NN / NPART);   // 256 rows per block
    float tau = __uint_as_float(scal[6]);
    uint32 cutoff = scal[7];
    int jg = t & 15, fg = t >> 4;

    float acc[4][8];
    #pragma unroll
    for (int a = 0; a < 4; ++a)
        #pragma unroll
        for (int bq = 0; bq < 8; ++bq) acc[a][bq] = 0.f;

    for (int ccnk = 0; ccnk < (NN / NPART) / 32; ++ccnk) {
        int ib = ibase + ccnk * 32;
        // stage masked+scaled S tile (vectorized)
        #pragma unroll
        for (int r = 0; r < 2; ++r) {
            int idx = r * 256 + t;          // 0..511
            int ii = idx >> 4;              // 0..31
            int j4 = (idx & 15) * 4;        // 0..60
            int gi = ib + ii;
            float di = dinv[gi];
            float4 v = *(const float4*)&S[(size_t)gi * NN + j0 + j4];
            uint32 fb = (uint32)(gi * NN + j0 + j4);
            float4 w;
            #pragma unroll
            for (int c = 0; c < 4; ++c) {
                float vv = (&v.x)[c];
                uint32 flat = fb + (uint32)c;
                bool sel = (vv > tau) || (vv == tau && flat <= cutoff);
                (&w.x)[c] = sel ? vv * di : 0.f;
            }
            *(float4*)&wsm[ii][j4] = w;
        }
        // stage h tile
        #pragma unroll
        for (int r = 0; r < 4; ++r) {
            int fidx = r * 256 + t;
            int ii = fidx >> 5, f4 = fidx & 31;
            *(float4*)&hsm[ii][f4 * 4] = *(const float4*)&h[(size_t)(ib + ii) * FF + f4 * 4];
        }
        __syncthreads();
        #pragma unroll 4
        for (int ii = 0; ii < 32; ++ii) {
            float4 w = *(float4*)&wsm[ii][jg * 4];
            float4 h0 = *(float4*)&hsm[ii][fg * 8];
            float4 h1 = *(float4*)&hsm[ii][fg * 8 + 4];
            float wv[4] = {w.x, w.y, w.z, w.w};
            float hv[8] = {h0.x, h0.y, h0.z, h0.w, h1.x, h1.y, h1.z, h1.w};
            #pragma unroll
            for (int a = 0; a < 4; ++a)
                #pragma unroll
                for (int bq = 0; bq < 8; ++bq) acc[a][bq] += wv[a] * hv[bq];
        }
        __syncthreads();
    }
    #pragma unroll
    for (int a = 0; a < 4; ++a) {
        int gj = j0 + jg * 4 + a;
        #pragma unroll
        for (int bq = 0; bq < 8; ++bq)
            part[((size_t)by * NN + gj) * FF + fg * 8 + bq] = acc[a][bq];
    }
}

// out[j][f] = b[f] + dinv[j] * (dinv[j]*h[j][f] + sum_p part[p][j][f])
__global__ __launch_bounds__(256) void k_reduce(const float* __restrict__ part,
                                                const float* __restrict__ h,
                                                const float* __restrict__ dinv,
                                                const float* __restrict__ bvec,
                                                float* __restrict__ out) {
    int idx4 = blockIdx.x * 256 + threadIdx.x;   // 65536 float4s
    int j = idx4 >> 5;
    int f4 = (idx4 & 31) * 4;
    size_t off = (size_t)j * FF + f4;
    float4 s = *(const float4*)&part[off];
    #pragma unroll
    for (int p = 1; p < NPART; ++p) {
        float4 v = *(const float4*)&part[(size_t)p * NN * FF + off];
        s.x += v.x; s.y += v.y; s.z += v.z; s.w += v.w;
    }
    float dj = dinv[j];
    float4 hv = *(const float4*)&h[off];
    float4 bv = *(const float4*)&bvec[f4];
    float4 o;
    o.x = bv.x + dj * (dj * hv.x + s.x);
    o.y = bv.y + dj * (dj * hv.y + s.y);
    o.z = bv.z + dj * (dj * hv.z + s.z);
    o.w = bv.w + dj * (dj * hv.w + s.w);
    *(float4*)&out[off] = o;
}

// ---- atomic fallback path (only if ws_size too small for partials) ----
__global__ __launch_bounds__(256) void k_agg_atomic(const float* __restrict__ S,
                                                    const float* __restrict__ h,
                                                    const float* __restrict__ dinv,
                                                    const uint32* __restrict__ scal,
                                                    float* __restrict__ accb) {
    __shared__ float wsm[32][68];
    __shared__ float hsm[32][132];
    int t = threadIdx.x;
    int j0 = blockIdx.x * 64;
    int ibase = blockIdx.y * 128;
    float tau = __uint_as_float(scal[6]);
    uint32 cutoff = scal[7];
    int jg = t & 15, fg = t >> 4;
    float acc[4][8];
    #pragma unroll
    for (int a = 0; a < 4; ++a)
        #pragma unroll
        for (int bq = 0; bq < 8; ++bq) acc[a][bq] = 0.f;
    for (int ccnk = 0; ccnk < 4; ++ccnk) {
        int ib = ibase + ccnk * 32;
        #pragma unroll
        for (int r = 0; r < 8; ++r) {
            int idx = r * 256 + t;
            int ii = idx >> 6, jj = idx & 63;
            int gi = ib + ii, gj = j0 + jj;
            float v = S[(size_t)gi * NN + gj];
            uint32 flat = (uint32)(gi * NN + gj);
            bool sel = (v > tau) || (v == tau && flat <= cutoff);
            wsm[ii][jj] = sel ? v * dinv[gi] : 0.f;
        }
        #pragma unroll
        for (int r = 0; r < 4; ++r) {
            int fidx = r * 256 + t;
            int ii = fidx >> 5, f4 = fidx & 31;
            *(float4*)&hsm[ii][f4 * 4] = *(const float4*)&h[(size_t)(ib + ii) * FF + f4 * 4];
        }
        __syncthreads();
        #pragma unroll 4
        for (int ii = 0; ii < 32; ++ii) {
            float4 w = *(float4*)&wsm[ii][jg * 4];
            float4 h0 = *(float4*)&hsm[ii][fg * 8];
            float4 h1 = *(float4*)&hsm[ii][fg * 8 + 4];
            float wv[4] = {w.x, w.y, w.z, w.w};
            float hv[8] = {h0.x, h0.y, h0.z, h0.w, h1.x, h1.y, h1.z, h1.w};
            #pragma unroll
            for (int a = 0; a < 4; ++a)
                #pragma unroll
                for (int bq = 0; bq < 8; ++bq) acc[a][bq] += wv[a] * hv[bq];
        }
        __syncthreads();
    }
    #pragma unroll
    for (int a = 0; a < 4; ++a) {
        int gj = j0 + jg * 4 + a;
        #pragma unroll
        for (int bq = 0; bq < 8; ++bq)
            atomicAdd(&accb[(size_t)gj * FF + fg * 8 + bq], acc[a][bq]);
    }
}

__global__ __launch_bounds__(256) void k_final(const float* __restrict__ accb,
                                               const float* __restrict__ h,
                                               const float* __restrict__ dinv,
                                               const float* __restrict__ bvec,
                                               float* __restrict__ out) {
    int idx4 = blockIdx.x * 256 + threadIdx.x;
    int j = idx4 >> 5;
    int f4 = (idx4 & 31) * 4;
    float dj = dinv[j];
    float4 a = *(const float4*)&accb[(size_t)j * FF + f4];
    float4 hv = *(const float4*)&h[(size_t)j * FF + f4];
    float4 bv = *(const float4*)&bvec[f4];
    float4 o;
    o.x = bv.x + dj * (dj * hv.x + a.x);
    o.y = bv.y + dj * (dj * hv.y + a.y);
    o.z = bv.z + dj * (dj * hv.z + a.z);
    o.w = bv.w + dj * (dj * hv.w + a.w);
    *(float4*)&out[(size_t)j * FF + f4] = o;
}

extern "C" void kernel_launch(void* const* d_in, const int* in_sizes, int n_in,
                              void* d_out, int out_size, void* d_ws, size_t ws_size,
                              hipStream_t stream) {
    const float* x = (const float*)d_in[0];   // [1,2048,128]
    const float* W = (const float*)d_in[1];   // [128,128]
    const float* b = (const float*)d_in[2];   // [128]
    float* out = (float*)d_out;

    if (ws_size < WS_NEEDED_ATOMIC) return;  // insufficient scratch: fail visibly

    char* ws = (char*)d_ws;
    float*  deg   = (float*)(ws + OFF_DEG);
    float*  dinv  = (float*)(ws + OFF_DINV);
    uint32* hist1 = (uint32*)(ws + OFF_HIST1);
    uint32* hist2 = (uint32*)(ws + OFF_HIST2);
    uint32* scal  = (uint32*)(ws + OFF_SCAL);
    float*  candV = (float*)(ws + OFF_CANDV);
    uint32* candF = (uint32*)(ws + OFF_CANDF);
    float*  accb  = (float*)(ws + OFF_ACC);
    float*  h     = (float*)(ws + OFF_H);
    float*  S     = (float*)(ws + OFF_S);
    float*  part  = (float*)(ws + OFF_PART);

    hipMemsetAsync(ws, 0, ZERO_BYTES, stream);

    k_h<<<NN, 128, 0, stream>>>(x, W, h);
    k_sim<<<dim3(32, 32), 256, 0, stream>>>(x, S, hist1);
    k_scan<<<1, 256, 0, stream>>>(hist1, scal, 1);
    k_hist2<<<512, 256, 0, stream>>>((const float4*)S, hist2, scal);
    k_scan<<<1, 256, 0, stream>>>(hist2, scal, 2);
    k_cand<<<512, 256, 0, stream>>>(S, candV, candF, scal);
    k_pick<<<1, 256, 0, stream>>>(candV, candF, scal);
    k_deg<<<dim3(8, 32), 256, 0, stream>>>(S, scal, deg);
    k_dinv<<<8, 256, 0, stream>>>(deg, dinv);
    if (ws_size >= WS_NEEDED_PART) {
        k_agg_part<<<dim3(32, NPART), 256, 0, stream>>>(S, h, dinv, scal, part);
        k_reduce<<<256, 256, 0, stream>>>(part, h, dinv, b, out);
    } else {
        k_agg_atomic<<<dim3(32, 16), 256, 0, stream>>>(S, h, dinv, scal, accb);
        k_final<<<256, 256, 0, stream>>>(accb, h, dinv, b, out);
    }
}

// Round 5
// 136.400 us; speedup vs baseline: 1.9795x; 1.0829x over previous
//
#include <hip/hip_runtime.h>

typedef unsigned int uint32;
typedef __attribute__((ext_vector_type(8))) _Float16 f16x8;
typedef __attribute__((ext_vector_type(4))) float f32x4;

#define NN 2048
#define FF 128
#define KEEPK 1258291u      // int(0.3 * 2048 * 2048)
#define NB 2048             // histogram bins per level
#define LO1 (-4.0f)
#define BINW1 0.0625f       // 2^-4, exact
#define INV1 16.0f
#define INV2 32768.0f       // 2048 / BINW1 = 2^15, exact
#define CAND_CAP 16384
#define NPART 8             // i-chunks for atomic-free aggregation
#define LO_SCALE 2048.0f    // 2^11: keep fp16 lo-part in normal range
#define LO_UNSCALE 4.8828125e-4f  // 2^-11

// workspace layout (bytes)
#define OFF_DEG   (0u)               // float[2048]
#define OFF_DINV  (8u*1024u)         // float[2048]
#define OFF_HIST1 (16u*1024u)        // uint[2048]
#define OFF_HIST2 (24u*1024u)        // uint[2048]
#define OFF_SCAL  (32u*1024u)        // uint[64]: 0=B1 1=K2 2=B2 3=need 5=cand_count 6=tau 7=cutoff
#define OFF_CANDV (40u*1024u)        // float[16384] = 64K
#define OFF_CANDF (104u*1024u)       // uint[16384]  = 64K
#define OFF_XHI   (168u*1024u)       // fp16 hi(x)  [2048][128] = 512K
#define OFF_XLO   (680u*1024u)       // fp16 (x-hi)*2048 [2048][128] = 512K
#define OFF_H     (1192u*1024u)      // float h [2048][128] = 1 MB
#define OFF_S     (2216u*1024u)      // float[2048*2048] = 16 MB
#define OFF_PART  (OFF_S + (uint32)NN*NN*4u)   // float[NPART][2048][128] = 8 MB
#define WS_NEEDED ((size_t)OFF_PART + (size_t)NPART*NN*FF*4u)
#define ZERO_BYTES (40u*1024u)       // deg + dinv + hist1 + hist2 + scal

__device__ __forceinline__ int bin_of(float v, float lo, float inv) {
    int b = (int)floorf((v - lo) * inv);
    return b < 0 ? 0 : (b > NB - 1 ? NB - 1 : b);
}

// h = X*W (fp32); also emit split-fp16 x: xhi = fp16(x), xlo = fp16((x-xhi)*2048)
__global__ __launch_bounds__(128) void k_h(const float* __restrict__ x,
                                           const float* __restrict__ W,
                                           unsigned short* __restrict__ xhi,
                                           unsigned short* __restrict__ xlo,
                                           float* __restrict__ h) {
    __shared__ float xs[FF];
    int row = blockIdx.x;
    int f = threadIdx.x;
    float xv = x[row * FF + f];
    xs[f] = xv;
    union { _Float16 fh; unsigned short u; } cv;
    cv.fh = (_Float16)xv;
    xhi[row * FF + f] = cv.u;
    float back = (float)cv.fh;
    cv.fh = (_Float16)((xv - back) * LO_SCALE);
    xlo[row * FF + f] = cv.u;
    __syncthreads();
    float a0 = 0.f, a1 = 0.f, a2 = 0.f, a3 = 0.f;
    #pragma unroll 8
    for (int k = 0; k < FF; k += 4) {
        a0 += xs[k + 0] * W[(k + 0) * FF + f];
        a1 += xs[k + 1] * W[(k + 1) * FF + f];
        a2 += xs[k + 2] * W[(k + 2) * FF + f];
        a3 += xs[k + 3] * W[(k + 3) * FF + f];
    }
    h[row * FF + f] = (a0 + a1) + (a2 + a3);
}

// S = X*X^T - I at ~fp32 accuracy via split-fp16 MFMA:
//   S = hi.hi^T + 2^-11 * (hi.lo^T + lo.hi^T),  lo pre-scaled by 2^11.
// 64x64 tile per block, 4 waves (2x2), each wave 32x32 (2x2 16x16 frags).
// LDS arrays [64 rows][16 chunks of 8 fp16], 16B-chunk XOR swizzle. Fused hist1.
__global__ __launch_bounds__(256) void k_sim(const unsigned short* __restrict__ xhi,
                                             const unsigned short* __restrict__ xlo,
                                             float* __restrict__ S,
                                             uint32* __restrict__ hist1) {
    __shared__ unsigned short Ahi[64 * 128];  // 16 KB each
    __shared__ unsigned short Alo[64 * 128];
    __shared__ unsigned short Bhi[64 * 128];
    __shared__ unsigned short Blo[64 * 128];
    __shared__ uint32 hs[NB];                 // 8 KB
    int t = threadIdx.x;
    for (int i = t; i < NB; i += 256) hs[i] = 0;
    int i0 = blockIdx.y * 64, j0 = blockIdx.x * 64;
    #pragma unroll
    for (int u = 0; u < 4; ++u) {
        int id = u * 256 + t;           // 1024 chunks per array (64 rows x 16)
        int r = id >> 4, c = id & 15;
        int sl = (c ^ (r & 7)) * 8;     // swizzled elem offset
        *(uint4*)&Ahi[r * 128 + sl] = *(const uint4*)&xhi[(size_t)(i0 + r) * FF + c * 8];
        *(uint4*)&Alo[r * 128 + sl] = *(const uint4*)&xlo[(size_t)(i0 + r) * FF + c * 8];
        *(uint4*)&Bhi[r * 128 + sl] = *(const uint4*)&xhi[(size_t)(j0 + r) * FF + c * 8];
        *(uint4*)&Blo[r * 128 + sl] = *(const uint4*)&xlo[(size_t)(j0 + r) * FF + c * 8];
    }
    __syncthreads();

    int wid = t >> 6, l = t & 63;
    int wy = wid >> 1, wx = wid & 1;
    int lr = l & 15, lg = l >> 4;
    f32x4 acc1[2][2], acc2[2][2];
    #pragma unroll
    for (int m = 0; m < 2; ++m)
        #pragma unroll
        for (int n = 0; n < 2; ++n) {
            acc1[m][n] = (f32x4){0.f, 0.f, 0.f, 0.f};
            acc2[m][n] = (f32x4){0.f, 0.f, 0.f, 0.f};
        }

    #pragma unroll
    for (int kk = 0; kk < 4; ++kk) {
        f16x8 ah[2], al[2], bh[2], bl[2];
        int chunk = kk * 4 + lg;
        #pragma unroll
        for (int m = 0; m < 2; ++m) {
            int row = wy * 32 + m * 16 + lr;
            int off = row * 128 + ((chunk ^ (row & 7)) * 8);
            ah[m] = *(f16x8*)&Ahi[off];
            al[m] = *(f16x8*)&Alo[off];
        }
        #pragma unroll
        for (int n = 0; n < 2; ++n) {
            int row = wx * 32 + n * 16 + lr;
            int off = row * 128 + ((chunk ^ (row & 7)) * 8);
            bh[n] = *(f16x8*)&Bhi[off];
            bl[n] = *(f16x8*)&Blo[off];
        }
        #pragma unroll
        for (int m = 0; m < 2; ++m)
            #pragma unroll
            for (int n = 0; n < 2; ++n) {
                acc1[m][n] = __builtin_amdgcn_mfma_f32_16x16x32_f16(ah[m], bh[n], acc1[m][n], 0, 0, 0);
                acc2[m][n] = __builtin_amdgcn_mfma_f32_16x16x32_f16(ah[m], bl[n], acc2[m][n], 0, 0, 0);
                acc2[m][n] = __builtin_amdgcn_mfma_f32_16x16x32_f16(al[m], bh[n], acc2[m][n], 0, 0, 0);
            }
    }

    // C-write (col=lane&15, row=(lane>>4)*4+reg) + fused hist
    #pragma unroll
    for (int m = 0; m < 2; ++m) {
        #pragma unroll
        for (int n = 0; n < 2; ++n) {
            #pragma unroll
            for (int r = 0; r < 4; ++r) {
                int gi = i0 + wy * 32 + m * 16 + lg * 4 + r;
                int gj = j0 + wx * 32 + n * 16 + lr;
                float v = acc1[m][n][r] + acc2[m][n][r] * LO_UNSCALE;
                if (gi == gj) v -= 1.0f;          // subtract eye
                S[(size_t)gi * NN + gj] = v;
                atomicAdd(&hs[bin_of(v, LO1, INV1)], 1u);
            }
        }
    }
    __syncthreads();
    for (int i = t; i < NB; i += 256) {
        uint32 v = hs[i];
        if (v) atomicAdd(&hist1[i], v);
    }
}

// level-2 histogram: refine bin B1
__global__ __launch_bounds__(256) void k_hist2(const float4* __restrict__ S4,
                                               uint32* __restrict__ hist,
                                               const uint32* __restrict__ scal) {
    __shared__ uint32 hs[NB];
    int t = threadIdx.x;
    for (int i = t; i < NB; i += blockDim.x) hs[i] = 0;
    __syncthreads();
    int B1 = (int)scal[0];
    float lo2 = LO1 + (float)B1 * BINW1;
    int total4 = (NN * NN) / 4;
    for (int idx = blockIdx.x * blockDim.x + t; idx < total4; idx += gridDim.x * blockDim.x) {
        float4 v = S4[idx];
        #pragma unroll
        for (int c = 0; c < 4; ++c) {
            float xv = (&v.x)[c];
            if (bin_of(xv, LO1, INV1) == B1) {
                atomicAdd(&hs[bin_of(xv, lo2, INV2)], 1u);
            }
        }
    }
    __syncthreads();
    for (int i = t; i < NB; i += blockDim.x) {
        uint32 v = hs[i];
        if (v) atomicAdd(&hist[i], v);
    }
}

// find bin containing K-th largest (descending cumulative)
__global__ __launch_bounds__(256) void k_scan(const uint32* __restrict__ hist,
                                              uint32* __restrict__ scal, int level) {
    __shared__ uint32 csum[256];
    int t = threadIdx.x;
    uint32 s = 0;
    #pragma unroll
    for (int u = 0; u < 8; ++u) s += hist[t * 8 + u];
    csum[t] = s;
    __syncthreads();
    if (t == 0) {
        uint32 K = (level == 1) ? KEEPK : scal[1];
        uint32 cum = 0;
        int cb = 255;
        for (; cb > 0; --cb) {
            if (cum + csum[cb] >= K) break;
            cum += csum[cb];
        }
        int b;
        for (b = cb * 8 + 7; b > cb * 8; --b) {
            if (cum + hist[b] >= K) break;
            cum += hist[b];
        }
        if (level == 1) { scal[0] = (uint32)b; scal[1] = K - cum; }
        else           { scal[2] = (uint32)b; scal[3] = K - cum; }
    }
}

// gather candidate (value, flat index) pairs in the final bin
__global__ __launch_bounds__(256) void k_cand(const float* __restrict__ S,
                                              float* __restrict__ candV,
                                              uint32* __restrict__ candF,
                                              uint32* __restrict__ scal) {
    int B1 = (int)scal[0], B2 = (int)scal[2];
    float lo2 = LO1 + (float)B1 * BINW1;
    int total = NN * NN;
    for (int idx = blockIdx.x * blockDim.x + threadIdx.x; idx < total;
         idx += gridDim.x * blockDim.x) {
        float v = S[idx];
        if (bin_of(v, LO1, INV1) == B1 && bin_of(v, lo2, INV2) == B2) {
            uint32 p = atomicAdd(&scal[5], 1u);
            if (p < CAND_CAP) { candV[p] = v; candF[p] = (uint32)idx; }
        }
    }
}

// exact tau + tie cutoff: partial selection sort (desc value, asc flat idx)
__global__ __launch_bounds__(256) void k_pick(const float* __restrict__ candV,
                                              const uint32* __restrict__ candF,
                                              uint32* __restrict__ scal) {
    __shared__ float sv[4096];
    __shared__ uint32 sf[4096];
    int t = threadIdx.x;
    uint32 cnt = scal[5];
    if (cnt > 4096u) cnt = 4096u;
    for (uint32 i = t; i < cnt; i += 256u) { sv[i] = candV[i]; sf[i] = candF[i]; }
    __syncthreads();
    if (t == 0) {
        uint32 need = scal[3];
        if (need > cnt) need = cnt;
        if (cnt == 0) { scal[6] = __float_as_uint(3.0e38f); scal[7] = 0u; return; }
        if (need == 0) need = 1;
        for (uint32 s = 0; s < need; ++s) {
            uint32 best = s;
            for (uint32 q = s + 1; q < cnt; ++q) {
                if (sv[q] > sv[best] || (sv[q] == sv[best] && sf[q] < sf[best])) best = q;
            }
            float tv = sv[s]; sv[s] = sv[best]; sv[best] = tv;
            uint32 tf = sf[s]; sf[s] = sf[best]; sf[best] = tf;
        }
        scal[6] = __float_as_uint(sv[need - 1]);
        scal[7] = sf[need - 1];
    }
}

// deg[j] = sum of selected sim[i][j] over i (self-loop +1 added in k_dinv)
__global__ __launch_bounds__(256) void k_deg(const float* __restrict__ S,
                                             const uint32* __restrict__ scal,
                                             float* __restrict__ deg) {
    int j = blockIdx.x * 256 + threadIdx.x;
    int i0 = blockIdx.y * 64;
    float tau = __uint_as_float(scal[6]);
    uint32 cutoff = scal[7];
    float p = 0.f;
    #pragma unroll 4
    for (int ii = 0; ii < 64; ++ii) {
        int i = i0 + ii;
        float v = S[(size_t)i * NN + j];
        uint32 flat = (uint32)(i * NN + j);
        if (v > tau || (v == tau && flat <= cutoff)) p += v;
    }
    atomicAdd(&deg[j], p);
}

__global__ __launch_bounds__(256) void k_dinv(const float* __restrict__ deg,
                                              float* __restrict__ dinv) {
    int j = blockIdx.x * 256 + threadIdx.x;
    dinv[j] = rsqrtf(deg[j] + 1.0f);   // +1.0 = self-loop; always > 0
}

// part[by][j][f] = sum_{i in chunk by} sel(i,j) * S[i][j] * dinv[i] * h[i][f]
// Atomic-free fp32 SIMT (R2-proven): each block owns a (j-tile, i-chunk) slice.
__global__ __launch_bounds__(256) void k_agg_part(const float* __restrict__ S,
                                                  const float* __restrict__ h,
                                                  const float* __restrict__ dinv,
                                                  const uint32* __restrict__ scal,
                                                  float* __restrict__ part) {
    __shared__ float wsm[32][68];    // [ii][jj], padded
    __shared__ float hsm[32][132];   // [ii][f], padded
    int t = threadIdx.x;
    int j0 = blockIdx.x * 64;
    int by = blockIdx.y;
    int ibase = by * (NN / NPART);   // 256 rows per block
    float tau = __uint_as_float(scal[6]);
    uint32 cutoff = scal[7];
    int jg = t & 15, fg = t >> 4;

    float acc[4][8];
    #pragma unroll
    for (int a = 0; a < 4; ++a)
        #pragma unroll
        for (int bq = 0; bq < 8; ++bq) acc[a][bq] = 0.f;

    for (int ccnk = 0; ccnk < (NN / NPART) / 32; ++ccnk) {
        int ib = ibase + ccnk * 32;
        // stage masked+scaled S tile (vectorized)
        #pragma unroll
        for (int r = 0; r < 2; ++r) {
            int idx = r * 256 + t;          // 0..511
            int ii = idx >> 4;              // 0..31
            int j4 = (idx & 15) * 4;        // 0..60
            int gi = ib + ii;
            float di = dinv[gi];
            float4 v = *(const float4*)&S[(size_t)gi * NN + j0 + j4];
            uint32 fb = (uint32)(gi * NN + j0 + j4);
            float4 w;
            #pragma unroll
            for (int c = 0; c < 4; ++c) {
                float vv = (&v.x)[c];
                uint32 flat = fb + (uint32)c;
                bool sel = (vv > tau) || (vv == tau && flat <= cutoff);
                (&w.x)[c] = sel ? vv * di : 0.f;
            }
            *(float4*)&wsm[ii][j4] = w;
        }
        // stage h tile
        #pragma unroll
        for (int r = 0; r < 4; ++r) {
            int fidx = r * 256 + t;
            int ii = fidx >> 5, f4 = fidx & 31;
            *(float4*)&hsm[ii][f4 * 4] = *(const float4*)&h[(size_t)(ib + ii) * FF + f4 * 4];
        }
        __syncthreads();
        #pragma unroll 4
        for (int ii = 0; ii < 32; ++ii) {
            float4 w = *(float4*)&wsm[ii][jg * 4];
            float4 h0 = *(float4*)&hsm[ii][fg * 8];
            float4 h1 = *(float4*)&hsm[ii][fg * 8 + 4];
            float wv[4] = {w.x, w.y, w.z, w.w};
            float hv[8] = {h0.x, h0.y, h0.z, h0.w, h1.x, h1.y, h1.z, h1.w};
            #pragma unroll
            for (int a = 0; a < 4; ++a)
                #pragma unroll
                for (int bq = 0; bq < 8; ++bq) acc[a][bq] += wv[a] * hv[bq];
        }
        __syncthreads();
    }
    #pragma unroll
    for (int a = 0; a < 4; ++a) {
        int gj = j0 + jg * 4 + a;
        #pragma unroll
        for (int bq = 0; bq < 8; ++bq)
            part[((size_t)by * NN + gj) * FF + fg * 8 + bq] = acc[a][bq];
    }
}

// out[j][f] = b[f] + dinv[j] * (dinv[j]*h[j][f] + sum_p part[p][j][f])
__global__ __launch_bounds__(256) void k_reduce(const float* __restrict__ part,
                                                const float* __restrict__ h,
                                                const float* __restrict__ dinv,
                                                const float* __restrict__ bvec,
                                                float* __restrict__ out) {
    int idx4 = blockIdx.x * 256 + threadIdx.x;   // 65536 float4s
    int j = idx4 >> 5;
    int f4 = (idx4 & 31) * 4;
    size_t off = (size_t)j * FF + f4;
    float4 s = *(const float4*)&part[off];
    #pragma unroll
    for (int p = 1; p < NPART; ++p) {
        float4 v = *(const float4*)&part[(size_t)p * NN * FF + off];
        s.x += v.x; s.y += v.y; s.z += v.z; s.w += v.w;
    }
    float dj = dinv[j];
    float4 hv = *(const float4*)&h[off];
    float4 bv = *(const float4*)&bvec[f4];
    float4 o;
    o.x = bv.x + dj * (dj * hv.x + s.x);
    o.y = bv.y + dj * (dj * hv.y + s.y);
    o.z = bv.z + dj * (dj * hv.z + s.z);
    o.w = bv.w + dj * (dj * hv.w + s.w);
    *(float4*)&out[off] = o;
}

extern "C" void kernel_launch(void* const* d_in, const int* in_sizes, int n_in,
                              void* d_out, int out_size, void* d_ws, size_t ws_size,
                              hipStream_t stream) {
    const float* x = (const float*)d_in[0];   // [1,2048,128]
    const float* W = (const float*)d_in[1];   // [128,128]
    const float* b = (const float*)d_in[2];   // [128]
    float* out = (float*)d_out;

    if (ws_size < WS_NEEDED) return;  // insufficient scratch: fail visibly

    char* ws = (char*)d_ws;
    float*          deg   = (float*)(ws + OFF_DEG);
    float*          dinv  = (float*)(ws + OFF_DINV);
    uint32*         hist1 = (uint32*)(ws + OFF_HIST1);
    uint32*         hist2 = (uint32*)(ws + OFF_HIST2);
    uint32*         scal  = (uint32*)(ws + OFF_SCAL);
    float*          candV = (float*)(ws + OFF_CANDV);
    uint32*         candF = (uint32*)(ws + OFF_CANDF);
    unsigned short* xhi   = (unsigned short*)(ws + OFF_XHI);
    unsigned short* xlo   = (unsigned short*)(ws + OFF_XLO);
    float*          h     = (float*)(ws + OFF_H);
    float*          S     = (float*)(ws + OFF_S);
    float*          part  = (float*)(ws + OFF_PART);

    hipMemsetAsync(ws, 0, ZERO_BYTES, stream);

    k_h<<<NN, 128, 0, stream>>>(x, W, xhi, xlo, h);
    k_sim<<<dim3(32, 32), 256, 0, stream>>>(xhi, xlo, S, hist1);
    k_scan<<<1, 256, 0, stream>>>(hist1, scal, 1);
    k_hist2<<<512, 256, 0, stream>>>((const float4*)S, hist2, scal);
    k_scan<<<1, 256, 0, stream>>>(hist2, scal, 2);
    k_cand<<<512, 256, 0, stream>>>(S, candV, candF, scal);
    k_pick<<<1, 256, 0, stream>>>(candV, candF, scal);
    k_deg<<<dim3(8, 32), 256, 0, stream>>>(S, scal, deg);
    k_dinv<<<8, 256, 0, stream>>>(deg, dinv);
    k_agg_part<<<dim3(32, NPART), 256, 0, stream>>>(S, h, dinv, scal, part);
    k_reduce<<<256, 256, 0, stream>>>(part, h, dinv, b, out);
}